// Round 5
// baseline (1387.034 us; speedup 1.0000x reference)
//
#include <hip/hip_runtime.h>
#include <hip/hip_bf16.h>
#include <math.h>

// Problem constants (B=8, S=4096, H=1024, E=64, Hh=512)
#define N_TOK 32768
#define HDIM 1024
#define HH 512
#define NOUT 576   // 512 h-cols + 64 router cols
#define CT 16      // cols per thread/block tile
#define NCT 36     // 576/16 col-tiles
#define THREADS 256
// OpenBLAS sgemm k-panel boundaries (SGEMM_DEFAULT_Q = 384)
// res = ((P0 + P1) + P2), each Pi a sequential fmaf chain.

// Output layout in d_out (all float32):
#define OFF_SELW 0
#define OFF_SELI 262144
#define OFF_CONF 524288
#define OFF_LOG  557056

// Static device scratch
__device__ __attribute__((aligned(256))) float g_Bmat[HDIM * NOUT]; // [k][j]
__device__ double g_partial[N_TOK * 32];   // per-token, per-16-col-tile fp64 partials

// ---------------- kernel 0: build fused B matrix ----------------
__global__ __launch_bounds__(256) void k_build(const float* __restrict__ W1,
                                               const float* __restrict__ Wr) {
  int idx = blockIdx.x * 256 + threadIdx.x;   // < HDIM*NOUT = 589824 exactly
  int k = idx / NOUT;
  int j = idx - k * NOUT;
  float v = (j < HH) ? W1[(size_t)j * HDIM + k] : Wr[(size_t)(j - HH) * HDIM + k];
  g_Bmat[idx] = v;
}

// ---------------- kernel 1: GEMM, SGPR-broadcast B, no LDS ----------------
// Thread = 1 token row x 16 cols. A[m][k] per-lane VGPR (own row, float4 loads);
// B[k][j] wave-uniform -> scalar loads -> v_fma with SGPR operand.
// Per-element fp32 fmaf chain, k ascending, panel folds at 384/768
// (bit-exact OpenBLAS sgemm reduction order).
__global__ __launch_bounds__(THREADS, 8) void k_gemm(const float* __restrict__ A,
                                                     const float* __restrict__ b1,
                                                     const float* __restrict__ W2,
                                                     const float* __restrict__ b_router,
                                                     float* __restrict__ out_logits) {
  // XCD swizzle: all 36 col-tiles of one token-group land on one XCD
  int bid = blockIdx.x;            // 0..4607
  int xcd = bid & 7;
  int s   = bid >> 3;              // 0..575
  int ct  = s % NCT;               // col-tile 0..35
  int tg  = xcd + 8 * (s / NCT);   // token-group 0..127

  const int m  = tg * 256 + threadIdx.x;   // token id
  const int j0 = ct * CT;                  // first col of tile

  const float* __restrict__ Ag = A + (size_t)m * HDIM;
  const float* __restrict__ Bg = g_Bmat + j0;   // uniform base

  float acc[CT], carry[CT];
  #pragma unroll
  for (int c = 0; c < CT; ++c) { acc[c] = 0.f; carry[c] = 0.f; }

  const int kb[4] = {0, 384, 768, 1024};
  #pragma unroll
  for (int p = 0; p < 3; ++p) {
    for (int k0 = kb[p]; k0 < kb[p + 1]; k0 += 4) {
      float4 av = *(const float4*)(Ag + k0);
      const float a4[4] = {av.x, av.y, av.z, av.w};
      #pragma unroll
      for (int kk = 0; kk < 4; ++kk) {
        const float* __restrict__ brow = Bg + (size_t)(k0 + kk) * NOUT;
        float a = a4[kk];
        #pragma unroll
        for (int c = 0; c < CT; ++c)
          acc[c] = fmaf(a, brow[c], acc[c]);    // B uniform -> SGPR operand
      }
    }
    // panel fold (plain fp32 add; carry starts at 0 so P0 fold is exact)
    #pragma unroll
    for (int c = 0; c < CT; ++c) { carry[c] = carry[c] + acc[c]; acc[c] = 0.f; }
  }
  // carry[] now holds res = ((P0 + P1) + P2)

  if (ct < 32) {
    // h-tile: fp32 h = relu(res + b1) exactly as np; fp64 partial of h . W2
    double sacc = 0.0;
    #pragma unroll
    for (int c = 0; c < CT; ++c) {
      float h = fmaxf(carry[c] + b1[j0 + c], 0.f);
      sacc = fma((double)h, (double)W2[j0 + c], sacc);
    }
    g_partial[(size_t)m * 32 + ct] = sacc;
  } else {
    // router tile: logits = res + b_router (fp32), cols (ct-32)*16 ..+15
    int jr = (ct - 32) * CT;
    float o[CT];
    #pragma unroll
    for (int c = 0; c < CT; ++c) o[c] = carry[c] + b_router[jr + c];
    float* dst = out_logits + (size_t)m * 64 + jr;
    #pragma unroll
    for (int c4 = 0; c4 < 4; ++c4)
      *(float4*)(dst + c4 * 4) =
          make_float4(o[c4 * 4], o[c4 * 4 + 1], o[c4 * 4 + 2], o[c4 * 4 + 3]);
  }
}

// ---------------- kernel 2: per-token postlude ----------------
// fp32 softmax exactly mirroring np: max-subtract, expf, numpy pairwise-8 sum,
// true division. Confidence/dk in fp64 (exact). Single in-place x[64].
__global__ __launch_bounds__(256, 2) void k_post(const float* __restrict__ b2,
                                                 float* __restrict__ d_out) {
  int tk = blockIdx.x * 256 + threadIdx.x;   // < 32768

  // confidence: fp64 sum of the 32 tile partials (ascending, exact-enough)
  double ca = (double)b2[0];
  #pragma unroll
  for (int jj = 0; jj < 32; ++jj) ca += g_partial[(size_t)tk * 32 + jj];
  double conf = 1.0 / (1.0 + exp(-ca));
  double dkf  = 1.0 + 7.0 * (1.0 - conf);
  double dkr  = rint(dkf);   // round half-to-even, matches jnp.round
  int dk = (int)fmin(fmax(dkr, 1.0), 8.0);

  // fp32 softmax over the 64 logits we wrote (re-read: bitwise identical)
  const float* logits = d_out + OFF_LOG + (size_t)tk * 64;
  float x[64];
  #pragma unroll
  for (int e4 = 0; e4 < 16; ++e4)
    *(float4*)&x[e4 * 4] = *(const float4*)&logits[e4 * 4];

  float mx = x[0];
  #pragma unroll
  for (int e = 1; e < 64; ++e) mx = fmaxf(mx, x[e]);

  #pragma unroll
  for (int e = 0; e < 64; ++e) x[e] = expf(x[e] - mx);

  // numpy scalar pairwise_sum base case (n=64 <= 128): 8 strided accumulators
  float r[8];
  #pragma unroll
  for (int q = 0; q < 8; ++q) r[q] = x[q];
  #pragma unroll
  for (int b = 1; b < 8; ++b)
    #pragma unroll
    for (int q = 0; q < 8; ++q) r[q] += x[b * 8 + q];
  float ssum = ((r[0] + r[1]) + (r[2] + r[3])) + ((r[4] + r[5]) + (r[6] + r[7]));

  #pragma unroll
  for (int e = 0; e < 64; ++e) x[e] = x[e] / ssum;   // true IEEE division

  // stable top-8 (strict > : ties keep lowest index, matches lax.top_k)
  float* sel_w = d_out + OFF_SELW + (size_t)tk * 8;
  float* sel_i = d_out + OFF_SELI + (size_t)tk * 8;
  unsigned long long used = 0ull;
  #pragma unroll
  for (int slot = 0; slot < 8; ++slot) {
    float best = -1.f;
    int   bi   = 0;
    #pragma unroll
    for (int e = 0; e < 64; ++e) {
      bool ok = (((used >> e) & 1ull) == 0ull) && (x[e] > best);
      best = ok ? x[e] : best;
      bi   = ok ? e    : bi;
    }
    used |= (1ull << bi);
    bool active = slot < dk;
    sel_w[slot] = active ? best : 0.f;
    sel_i[slot] = active ? (float)bi : 0.f;
  }
  d_out[OFF_CONF + tk] = (float)conf;
}

extern "C" void kernel_launch(void* const* d_in, const int* in_sizes, int n_in,
                              void* d_out, int out_size, void* d_ws, size_t ws_size,
                              hipStream_t stream) {
  const float* hidden   = (const float*)d_in[0];
  const float* W_router = (const float*)d_in[1];
  const float* b_router = (const float*)d_in[2];
  const float* W1       = (const float*)d_in[3];
  const float* b1       = (const float*)d_in[4];
  const float* W2       = (const float*)d_in[5];
  const float* b2       = (const float*)d_in[6];
  float* out = (float*)d_out;

  k_build<<<(HDIM * NOUT) / 256, 256, 0, stream>>>(W1, W_router);
  k_gemm<<<(N_TOK / 256) * NCT, THREADS, 0, stream>>>(hidden, b1, W2, b_router,
                                                      out + OFF_LOG);
  k_post<<<N_TOK / 256, 256, 0, stream>>>(b2, out);
}

// Round 6
// 1004.845 us; speedup vs baseline: 1.3803x; 1.3803x over previous
//
#include <hip/hip_runtime.h>
#include <hip/hip_bf16.h>
#include <math.h>

// Problem constants (B=8, S=4096, H=1024, E=64, Hh=512)
#define N_TOK 32768
#define HDIM 1024
#define HH 512
#define NOUT 576   // 512 h-cols + 64 router cols
#define BM 128     // token rows per block
#define BK 32      // k-chunk
#define BCOL 32    // cols per block (2 waves x 16)
#define NCT 18     // 576/32 col-tiles
#define THREADS 128
// OpenBLAS sgemm: res = ((P0+P1)+P2), panels at k=384/768, sequential fmaf.

// Output layout in d_out (all float32):
#define OFF_SELW 0
#define OFF_SELI 262144
#define OFF_CONF 524288
#define OFF_LOG  557056

// Static device scratch
__device__ __attribute__((aligned(256))) float g_Bmat[HDIM * NOUT]; // [k][j]
__device__ double g_partial[N_TOK * 32];   // per-token, per-16-col fp64 partials

// ---------------- kernel 0: build fused B matrix ----------------
__global__ __launch_bounds__(256) void k_build(const float* __restrict__ W1,
                                               const float* __restrict__ Wr) {
  int idx = blockIdx.x * 256 + threadIdx.x;   // < HDIM*NOUT = 589824 exactly
  int k = idx / NOUT;
  int j = idx - k * NOUT;
  float v = (j < HH) ? W1[(size_t)j * HDIM + k] : Wr[(size_t)(j - HH) * HDIM + k];
  g_Bmat[idx] = v;
}

// ---------------- kernel 1: GEMM — LDS for A only, SGPR-broadcast B ----------
// Block: 128 tokens x 32 cols, 128 threads. Thread: rows {rg, rg+64} x 16 cols.
// A staged coalesced (8 lanes = 1 row chunk of 128 B) into As[k][m] (pad+1).
// B wave-uniform -> readfirstlane base -> s_load; v_fma takes SGPR operand.
// Per-element fp32 fmaf chain, k ascending, folds at 384/768 (bit-exact).
__global__ __launch_bounds__(THREADS, 4) void k_gemm(const float* __restrict__ A,
                                                     const float* __restrict__ b1,
                                                     const float* __restrict__ W2,
                                                     const float* __restrict__ b_router,
                                                     float* __restrict__ out_logits) {
  __shared__ float As[BK][BM + 1];   // 16.1 KB, As[k][m], +1 pad

  // XCD swizzle: the 18 col-tiles of one token-group land on one XCD
  int bid = blockIdx.x;            // 0..4607
  int xcd = bid & 7;
  int s   = bid >> 3;              // 0..575
  int ct  = s % NCT;               // col-tile 0..17
  int tg  = xcd + 8 * (s / NCT);   // token-group 0..255

  const int tid = threadIdx.x;     // 0..127
  const int rg  = tid & 63;        // row within half-tile
  const int cg  = tid >> 6;        // wave id = col-group (wave-uniform)
  const int cgu = __builtin_amdgcn_readfirstlane(cg);  // force SGPR
  const int m0  = tg * BM;
  const int j0  = ct * BCOL + cgu * 16;   // global col base for this wave

  // A staging map: idx = tid + pass*128 -> row = (tid>>3)+pass*16, c4 = tid&7
  const int srow = tid >> 3;       // 0..15
  const int sc4  = tid & 7;        // 0..7
  const float* __restrict__ Ag =
      A + (size_t)(m0 + srow) * HDIM + sc4 * 4;
  const float* __restrict__ Bg = g_Bmat + j0;   // SGPR-uniform base

  float acc[2][16], carry[2][16];
  #pragma unroll
  for (int r = 0; r < 2; ++r)
    #pragma unroll
    for (int c = 0; c < 16; ++c) { acc[r][c] = 0.f; carry[r][c] = 0.f; }

  for (int k0 = 0; k0 < HDIM; k0 += BK) {
    // panel fold at OpenBLAS KC boundaries (384, 768)
    if (k0 == 384 || k0 == 768) {
      #pragma unroll
      for (int r = 0; r < 2; ++r)
        #pragma unroll
        for (int c = 0; c < 16; ++c) {
          carry[r][c] = carry[r][c] + acc[r][c];  // plain fp32 add
          acc[r][c] = 0.f;
        }
    }

    // coalesced global load: 8 passes x (8 lanes x float4 = 128 B / row)
    float4 av[8];
    #pragma unroll
    for (int p = 0; p < 8; ++p)
      av[p] = *(const float4*)(Ag + (size_t)p * 16 * HDIM + k0);
    __syncthreads();  // protect LDS reuse from previous iteration
    #pragma unroll
    for (int p = 0; p < 8; ++p) {
      int row = srow + p * 16;
      int kb  = sc4 * 4;
      As[kb + 0][row] = av[p].x;
      As[kb + 1][row] = av[p].y;
      As[kb + 2][row] = av[p].z;
      As[kb + 3][row] = av[p].w;
    }
    __syncthreads();

    // inner: per k, B row (16 floats) via s_load; 32 v_fma with SGPR operand
    #pragma unroll 8
    for (int kk = 0; kk < BK; ++kk) {
      const float* __restrict__ brow = Bg + (size_t)(k0 + kk) * NOUT;
      float b[16];
      #pragma unroll
      for (int c = 0; c < 16; ++c) b[c] = brow[c];
      float a0 = As[kk][rg];
      float a1 = As[kk][rg + 64];
      #pragma unroll
      for (int c = 0; c < 16; ++c) {
        acc[0][c] = fmaf(a0, b[c], acc[0][c]);
        acc[1][c] = fmaf(a1, b[c], acc[1][c]);
      }
    }
  }

  // combine final panel in place: res = (P0+P1) + P2
  #pragma unroll
  for (int r = 0; r < 2; ++r)
    #pragma unroll
    for (int c = 0; c < 16; ++c) carry[r][c] = carry[r][c] + acc[r][c];

  const int rows[2] = {m0 + rg, m0 + rg + 64};
  if (ct < 16) {
    // h-tile: fp32 h = relu(res + b1); fp64 partial of h . W2
    const int pidx = ct * 2 + cgu;   // 0..31
    #pragma unroll
    for (int r = 0; r < 2; ++r) {
      double sacc = 0.0;
      #pragma unroll
      for (int c = 0; c < 16; ++c) {
        float h = fmaxf(carry[r][c] + b1[j0 + c], 0.f);
        sacc = fma((double)h, (double)W2[j0 + c], sacc);
      }
      g_partial[(size_t)rows[r] * 32 + pidx] = sacc;
    }
  } else {
    // router tile: logits = res + b_router (fp32)
    const int jr = j0 - HH;          // 0..63
    #pragma unroll
    for (int r = 0; r < 2; ++r) {
      float o[16];
      #pragma unroll
      for (int c = 0; c < 16; ++c) o[c] = carry[r][c] + b_router[jr + c];
      float* dst = out_logits + (size_t)rows[r] * 64 + jr;
      #pragma unroll
      for (int c4 = 0; c4 < 4; ++c4)
        *(float4*)(dst + c4 * 4) =
            make_float4(o[c4 * 4], o[c4 * 4 + 1], o[c4 * 4 + 2], o[c4 * 4 + 3]);
    }
  }
}

// ---------------- kernel 2: per-token postlude ----------------
// fp32 softmax exactly mirroring np: max-subtract, expf, numpy pairwise-8 sum,
// true division. Confidence/dk in fp64 (exact). Single in-place x[64].
__global__ __launch_bounds__(256, 2) void k_post(const float* __restrict__ b2,
                                                 float* __restrict__ d_out) {
  int tk = blockIdx.x * 256 + threadIdx.x;   // < 32768

  // confidence: fp64 sum of the 32 tile partials (ascending col order)
  double ca = (double)b2[0];
  #pragma unroll
  for (int jj = 0; jj < 32; ++jj) ca += g_partial[(size_t)tk * 32 + jj];
  double conf = 1.0 / (1.0 + exp(-ca));
  double dkf  = 1.0 + 7.0 * (1.0 - conf);
  double dkr  = rint(dkf);   // round half-to-even, matches jnp.round
  int dk = (int)fmin(fmax(dkr, 1.0), 8.0);

  // fp32 softmax over the 64 logits we wrote (re-read: bitwise identical)
  const float* logits = d_out + OFF_LOG + (size_t)tk * 64;
  float x[64];
  #pragma unroll
  for (int e4 = 0; e4 < 16; ++e4)
    *(float4*)&x[e4 * 4] = *(const float4*)&logits[e4 * 4];

  float mx = x[0];
  #pragma unroll
  for (int e = 1; e < 64; ++e) mx = fmaxf(mx, x[e]);

  #pragma unroll
  for (int e = 0; e < 64; ++e) x[e] = expf(x[e] - mx);

  // numpy scalar pairwise_sum base case (n=64 <= 128): 8 strided accumulators
  float r[8];
  #pragma unroll
  for (int q = 0; q < 8; ++q) r[q] = x[q];
  #pragma unroll
  for (int b = 1; b < 8; ++b)
    #pragma unroll
    for (int q = 0; q < 8; ++q) r[q] += x[b * 8 + q];
  float ssum = ((r[0] + r[1]) + (r[2] + r[3])) + ((r[4] + r[5]) + (r[6] + r[7]));

  #pragma unroll
  for (int e = 0; e < 64; ++e) x[e] = x[e] / ssum;   // true IEEE division

  // stable top-8 (strict > : ties keep lowest index, matches lax.top_k)
  float* sel_w = d_out + OFF_SELW + (size_t)tk * 8;
  float* sel_i = d_out + OFF_SELI + (size_t)tk * 8;
  unsigned long long used = 0ull;
  #pragma unroll
  for (int slot = 0; slot < 8; ++slot) {
    float best = -1.f;
    int   bi   = 0;
    #pragma unroll
    for (int e = 0; e < 64; ++e) {
      bool ok = (((used >> e) & 1ull) == 0ull) && (x[e] > best);
      best = ok ? x[e] : best;
      bi   = ok ? e    : bi;
    }
    used |= (1ull << bi);
    bool active = slot < dk;
    sel_w[slot] = active ? best : 0.f;
    sel_i[slot] = active ? (float)bi : 0.f;
  }
  d_out[OFF_CONF + tk] = (float)conf;
}

extern "C" void kernel_launch(void* const* d_in, const int* in_sizes, int n_in,
                              void* d_out, int out_size, void* d_ws, size_t ws_size,
                              hipStream_t stream) {
  const float* hidden   = (const float*)d_in[0];
  const float* W_router = (const float*)d_in[1];
  const float* b_router = (const float*)d_in[2];
  const float* W1       = (const float*)d_in[3];
  const float* b1       = (const float*)d_in[4];
  const float* W2       = (const float*)d_in[5];
  const float* b2       = (const float*)d_in[6];
  float* out = (float*)d_out;

  k_build<<<(HDIM * NOUT) / 256, 256, 0, stream>>>(W1, W_router);
  k_gemm<<<(N_TOK / BM) * NCT, THREADS, 0, stream>>>(hidden, b1, W2, b_router,
                                                     out + OFF_LOG);
  k_post<<<N_TOK / 256, 256, 0, stream>>>(b2, out);
}